// Round 2
// baseline (1085.229 us; speedup 1.0000x reference)
//
#include <hip/hip_runtime.h>
#include <math.h>

#define WAVE 64
constexpr int   CC      = 100;    // classes (fixed by problem)
constexpr int   MAXM    = 160;    // max thresholds per class (~0.05*P+1 ~= 132)
constexpr int   BUCKET  = 4096;   // per-class positive-score bucket capacity (P ~ 2621 +- 51)
constexpr float LSMOOTH = 0.1f;

// ---------------- K1: per-row softmax stats + positive-score scatter ----------------
__global__ __launch_bounds__(256) void k1_rowstats(
    const float* __restrict__ pred, const int* __restrict__ targets,
    const float* __restrict__ weight, float* __restrict__ L_out,
    float* __restrict__ bucket, int* __restrict__ cls_cnt,
    float* __restrict__ ce_partial, int N)
{
    const int lane = threadIdx.x & (WAVE - 1);
    const int wid  = threadIdx.x >> 6;
    const int wavesPerBlock = blockDim.x >> 6;
    const int gwave = blockIdx.x * wavesPerBlock + wid;
    const int totalWaves = gridDim.x * wavesPerBlock;

    const bool has2 = (lane < CC - WAVE);          // lanes 0..35 hold a 2nd class
    const float w0 = weight[lane];
    const float w1 = has2 ? weight[lane + WAVE] : 0.0f;
    float Wl = w0 + w1;                            // total weight sum
    #pragma unroll
    for (int off = 32; off; off >>= 1) Wl += __shfl_xor(Wl, off, WAVE);

    float ce_acc = 0.0f;
    for (int row = gwave; row < N; row += totalWaves) {
        const float* rp = pred + (size_t)row * CC;
        float v0 = rp[lane];
        float v1 = has2 ? rp[lane + WAVE] : -INFINITY;
        float vmax = fmaxf(v0, v1);
        #pragma unroll
        for (int off = 32; off; off >>= 1) vmax = fmaxf(vmax, __shfl_xor(vmax, off, WAVE));
        float z  = __expf(v0 - vmax) + (has2 ? __expf(v1 - vmax) : 0.0f);
        float ws = w0 * v0 + (has2 ? w1 * v1 : 0.0f);
        #pragma unroll
        for (int off = 32; off; off >>= 1) {
            z  += __shfl_xor(z,  off, WAVE);
            ws += __shfl_xor(ws, off, WAVE);
        }
        float L = vmax + __logf(z);                // log-sum-exp of the row
        int t = targets[row];
        float pt = rp[t];                          // wave-uniform cached load
        if (lane == 0) {
            L_out[row] = L;
            int slot = atomicAdd(&cls_cnt[t], 1);
            if (slot < BUCKET) bucket[(size_t)t * BUCKET + slot] = pt - L;
        }
        // ce_n = -( (1-LS)*w_t*lp_t + (LS/C)*sum_c w_c*lp_c ),  lp = pred - L
        ce_acc += -((1.0f - LSMOOTH) * weight[t] * (pt - L)
                    + (LSMOOTH / CC) * (ws - Wl * L));
    }
    __shared__ float cered[8];
    if (lane == 0) cered[wid] = ce_acc;
    __syncthreads();
    if (threadIdx.x == 0) {
        float s = 0.0f;
        for (int i = 0; i < wavesPerBlock; ++i) s += cered[i];
        ce_partial[blockIdx.x] = s;
    }
}

// --------- K2: per class, radix-select the m smallest positive scores ---------
// Replaces the 148us scan+bitonic-4096: load P~2621 keys to LDS, 4x8-bit MSB
// radix select for the (m-1)-rank key, collect the < kth keys, tiny bitonic-256.
__global__ __launch_bounds__(256) void k2_select(
    const float* __restrict__ bucket, const int* __restrict__ cls_cnt,
    float* __restrict__ u, int* __restrict__ m_arr, int* __restrict__ P_arr,
    float* __restrict__ wm_arr)
{
    __shared__ unsigned int keys[BUCKET];     // 16 KB
    __shared__ unsigned int hist[256];
    __shared__ unsigned int sel[256];
    __shared__ unsigned int s_prefix;
    __shared__ int s_rank;
    __shared__ int cnt_lt;
    const int c   = blockIdx.x;
    const int tid = threadIdx.x;
    const int P = min(cls_cnt[c], BUCKET);
    double Kd = 0.95 * (double)P;
    int kf = (int)floor(Kd);
    int m = P - kf;
    if (m > MAXM) m = MAXM;
    if (m < 0) m = 0;
    if (tid == 0) {
        m_arr[c] = m; P_arr[c] = P;
        wm_arr[c] = (float)((double)(kf + 1) - Kd);   // fractional last-step weight
        s_prefix = 0; s_rank = m - 1; cnt_lt = 0;
    }
    // monotone float->uint key: ascending uint order == ascending float order
    for (int i = tid; i < P; i += 256) {
        unsigned int b = __float_as_uint(bucket[(size_t)c * BUCKET + i]);
        keys[i] = (b & 0x80000000u) ? ~b : (b | 0x80000000u);
    }
    __syncthreads();
    if (m == 0) return;                                // uniform exit

    // 4 rounds of 8-bit radix select, MSB first -> exact key of rank m-1
    for (int shift = 24; shift >= 0; shift -= 8) {
        hist[tid] = 0;
        __syncthreads();
        unsigned int pref = s_prefix;
        for (int i = tid; i < P; i += 256) {
            unsigned int k = keys[i];
            bool match = (shift == 24) || ((k >> (shift + 8)) == pref);
            if (match) atomicAdd(&hist[(k >> shift) & 255u], 1u);
        }
        __syncthreads();
        if (tid == 0) {
            int r = s_rank;
            unsigned int cum = 0; int d = 0;
            for (; d < 256; ++d) {
                unsigned int h = hist[d];
                if (cum + h > (unsigned int)r) break;
                cum += h;
            }
            s_rank   = r - (int)cum;
            s_prefix = (pref << 8) | (unsigned int)d;
        }
        __syncthreads();
    }
    const unsigned int kth = s_prefix;

    // collect strictly-less keys (count <= m-1 <= 159), fill ties, pad to 256
    for (int i = tid; i < P; i += 256) {
        unsigned int k = keys[i];
        if (k < kth) {
            int pslot = atomicAdd(&cnt_lt, 1);
            sel[pslot] = k;
        }
    }
    __syncthreads();
    const int nlt = cnt_lt;
    for (int j = nlt + tid; j < 256; j += 256) sel[j] = (j < m) ? kth : 0xFFFFFFFFu;
    __syncthreads();

    // bitonic sort 256 (ascending), 1 element/thread
    for (int kk = 2; kk <= 256; kk <<= 1) {
        for (int j = kk >> 1; j > 0; j >>= 1) {
            int i = tid, ixj = tid ^ j;
            if (ixj > i) {
                unsigned int a = sel[i], b = sel[ixj];
                bool up = ((i & kk) == 0);
                if ((a > b) == up) { sel[i] = b; sel[ixj] = a; }
            }
            __syncthreads();
        }
    }
    if (tid < m) {
        unsigned int k = sel[tid];
        unsigned int b = (k & 0x80000000u) ? (k & 0x7fffffffu) : ~k;
        u[c * MAXM + tid] = __uint_as_float(b);        // m smallest, ascending
    }
}

// --------- K3: stream all scores, count below-threshold contributions ---------
__global__ __launch_bounds__(256) void k3_accum(
    const float4* __restrict__ pred4, const float* __restrict__ L,
    const float* __restrict__ u, const int* __restrict__ m_arr,
    int* __restrict__ g_cnt, int* __restrict__ g_sum, int total4)
{
    __shared__ float umax[CC];
    __shared__ int sm_m[CC];
    __shared__ int ls_cnt[CC], ls_sum[CC];
    for (int c = threadIdx.x; c < CC; c += blockDim.x) {
        int m = m_arr[c];
        sm_m[c] = m;
        umax[c] = (m > 0) ? u[c * MAXM + m - 1] : -INFINITY;
        ls_cnt[c] = 0; ls_sum[c] = 0;
    }
    __syncthreads();
    const int stride = gridDim.x * blockDim.x;
    for (int i = blockIdx.x * blockDim.x + threadIdx.x; i < total4; i += stride) {
        float4 v = pred4[i];
        int n  = i / (CC / 4);                 // 100 % 4 == 0: float4 never crosses a row
        int c0 = (i - n * (CC / 4)) * 4;
        float Ln = L[n];
        float sc[4] = { v.x - Ln, v.y - Ln, v.z - Ln, v.w - Ln };
        #pragma unroll
        for (int q = 0; q < 4; ++q) {
            int c = c0 + q;
            if (sc[q] < umax[c]) {             // ~5% take this path
                int m = sm_m[c];
                const float* uc = u + c * MAXM;
                int l = 0, r = m;              // upper_bound: # thresholds <= sc
                while (l < r) {
                    int mid = (l + r) >> 1;
                    if (uc[mid] <= sc[q]) l = mid + 1; else r = mid;
                }
                atomicAdd(&ls_cnt[c], 1);
                atomicAdd(&ls_sum[c], m - 1 - l);
            }
        }
    }
    __syncthreads();
    for (int c = threadIdx.x; c < CC; c += blockDim.x) {
        if (ls_cnt[c] > 0) {
            atomicAdd(&g_cnt[c], ls_cnt[c]);
            atomicAdd(&g_sum[c], ls_sum[c]);
        }
    }
}

// ---------------- K4: finalize (CE reduce + per-class pAUC + combine) ----------------
__global__ __launch_bounds__(256) void k4_final(
    const float* __restrict__ ce_partial, int nPartial,
    const float* __restrict__ weight, const int* __restrict__ P_arr,
    const int* __restrict__ m_arr, const float* __restrict__ wm_arr,
    const int* __restrict__ g_cnt, const int* __restrict__ g_sum,
    float* __restrict__ out, int N)
{
    __shared__ double r1[256], r2[256], r3[256];
    double ce = 0.0;
    for (int i = threadIdx.x; i < nPartial; i += blockDim.x) ce += (double)ce_partial[i];
    double p = 0.0, wsum = 0.0;
    for (int c = threadIdx.x; c < CC; c += blockDim.x) {
        int P = P_arr[c], m = m_arr[c];
        double wgt = (double)weight[c];
        long long Nn = (long long)N - P;
        if (P > 0 && Nn > 0 && m > 0) {
            double wm = (double)wm_arr[c];
            double S   = (double)g_sum[c] + wm * (double)g_cnt[c];
            double sub = 0.5 * (double)(m - 1) * (double)(m - 2) + wm * (double)(m - 1);
            double pc  = (S - sub) / ((double)Nn * (double)P);
            if (pc < 0.0) pc = 0.0;
            p += pc * wgt;
        }
        wsum += wgt;
    }
    r1[threadIdx.x] = ce; r2[threadIdx.x] = p; r3[threadIdx.x] = wsum;
    __syncthreads();
    for (int off = blockDim.x >> 1; off; off >>= 1) {
        if ((int)threadIdx.x < off) {
            r1[threadIdx.x] += r1[threadIdx.x + off];
            r2[threadIdx.x] += r2[threadIdx.x + off];
            r3[threadIdx.x] += r3[threadIdx.x + off];
        }
        __syncthreads();
    }
    if (threadIdx.x == 0) {
        double ce_loss = r1[0] / (double)N;
        double avg = r2[0] / (r3[0] * 0.05);           // MAX_PAUC = R1-R0 = 0.05
        avg = fmin(fmax(avg, 0.0), 1.0);
        out[0] = (float)(0.5 * ce_loss + 0.5 * (1.0 - avg * avg));
    }
}

extern "C" void kernel_launch(void* const* d_in, const int* in_sizes, int n_in,
                              void* d_out, int out_size, void* d_ws, size_t ws_size,
                              hipStream_t stream) {
    (void)n_in; (void)out_size; (void)ws_size;
    const float* pred    = (const float*)d_in[0];
    const int*   targets = (const int*)d_in[1];
    const float* weight  = (const float*)d_in[2];
    float* out = (float*)d_out;
    const int N = in_sizes[1];

    constexpr int K1_BLOCKS = 4096;
    char* base = (char*)d_ws;
    float* L_ws       = (float*)(base);                               // N floats
    float* ce_partial = (float*)(base + (size_t)N * 4);               // K1_BLOCKS floats
    char* p = base + (size_t)N * 4 + (size_t)K1_BLOCKS * 4;
    float* u      = (float*)p; p += (size_t)CC * MAXM * 4;
    int*   m_arr  = (int*)p;   p += CC * 4;
    int*   P_arr  = (int*)p;   p += CC * 4;
    float* wm_arr = (float*)p; p += CC * 4;
    int*   cls_cnt= (int*)p;   p += CC * 4;   // ---- zeroed region start (cls_cnt)
    int*   g_cnt  = (int*)p;   p += CC * 4;
    int*   g_sum  = (int*)p;   p += CC * 4;   // ---- zeroed region end
    float* bucket = (float*)p;                // CC*BUCKET floats (1.6 MB)

    hipMemsetAsync(cls_cnt, 0, (size_t)CC * 4 * 3, stream);           // cls_cnt+g_cnt+g_sum

    k1_rowstats<<<K1_BLOCKS, 256, 0, stream>>>(pred, targets, weight, L_ws,
                                               bucket, cls_cnt, ce_partial, N);
    k2_select<<<CC, 256, 0, stream>>>(bucket, cls_cnt, u, m_arr, P_arr, wm_arr);
    const int total4 = (int)((size_t)N * CC / 4);
    k3_accum<<<2048, 256, 0, stream>>>((const float4*)pred, L_ws, u, m_arr,
                                       g_cnt, g_sum, total4);
    k4_final<<<1, 256, 0, stream>>>(ce_partial, K1_BLOCKS, weight, P_arr, m_arr, wm_arr,
                                    g_cnt, g_sum, out, N);
}

// Round 3
// 346.203 us; speedup vs baseline: 3.1347x; 3.1347x over previous
//
#include <hip/hip_runtime.h>
#include <math.h>

#define WAVE 64
constexpr int   CC      = 100;    // classes (fixed by problem)
constexpr int   MAXM    = 160;    // max thresholds per class (~0.05*P+1 ~= 132)
constexpr int   BUCKET  = 4096;   // per-class positive-score bucket capacity (P ~ 2621 +- 51)
constexpr float LSMOOTH = 0.1f;

// ---------------- K1: per-row softmax stats, 16 lanes/row, 4 rows/wave ----------------
// No global atomics (round-2 regression: 262k atomicAdd over 100 counters = 795us stall).
__global__ __launch_bounds__(256) void k1_rowstats(
    const float* __restrict__ pred, const int* __restrict__ targets,
    const float* __restrict__ weight, float* __restrict__ L_out,
    float* __restrict__ pos_out, float* __restrict__ ce_partial, int N)
{
    const int lane = threadIdx.x & (WAVE - 1);
    const int wid  = threadIdx.x >> 6;
    const int wavesPerBlock = blockDim.x >> 6;
    const int gwave = blockIdx.x * wavesPerBlock + wid;
    const int totalWaves = gridDim.x * wavesPerBlock;
    const int g = lane >> 4;          // row group 0..3 within wave
    const int x = lane & 15;          // sub-lane within 16-lane row group

    // per-lane strided weights: columns x, x+16, ..., x+96 (7th only if x<4)
    float w[7];
    #pragma unroll
    for (int j = 0; j < 7; ++j) {
        int c = x + 16 * j;
        w[j] = (c < CC) ? weight[c] : 0.0f;
    }
    float Wl = 0.0f;
    #pragma unroll
    for (int j = 0; j < 7; ++j) Wl += w[j];
    #pragma unroll
    for (int off = 1; off < 16; off <<= 1) Wl += __shfl_xor(Wl, off, 16);

    float ce_acc = 0.0f;
    for (int rb = gwave * 4; rb < N; rb += totalWaves * 4) {
        const int row = rb + g;
        const float* rp = pred + (size_t)row * CC;
        float v[7];
        #pragma unroll
        for (int j = 0; j < 7; ++j) {
            int c = x + 16 * j;
            v[j] = (c < CC) ? rp[c] : -INFINITY;
        }
        float vmax = v[0];
        #pragma unroll
        for (int j = 1; j < 7; ++j) vmax = fmaxf(vmax, v[j]);
        #pragma unroll
        for (int off = 1; off < 16; off <<= 1) vmax = fmaxf(vmax, __shfl_xor(vmax, off, 16));
        float z = 0.0f, ws = 0.0f;
        #pragma unroll
        for (int j = 0; j < 7; ++j) {
            int c = x + 16 * j;
            if (c < CC) { z += __expf(v[j] - vmax); ws += w[j] * v[j]; }
        }
        #pragma unroll
        for (int off = 1; off < 16; off <<= 1) {
            z  += __shfl_xor(z,  off, 16);
            ws += __shfl_xor(ws, off, 16);
        }
        float L = vmax + __logf(z);                // row log-sum-exp
        if (x == 0) {
            int t = targets[row];
            float pt = rp[t];                      // L1-hot, row was just read
            L_out[row]   = L;
            pos_out[row] = pt - L;
            // ce_n = -( (1-LS)*w_t*lp_t + (LS/C)*sum_c w_c*lp_c ),  lp = pred - L
            ce_acc += -((1.0f - LSMOOTH) * weight[t] * (pt - L)
                        + (LSMOOTH / CC) * (ws - Wl * L));
        }
    }
    // full-wave reduce of ce_acc (only x==0 lanes are nonzero)
    #pragma unroll
    for (int off = 32; off; off >>= 1) ce_acc += __shfl_xor(ce_acc, off, WAVE);
    __shared__ float cered[8];
    if (lane == 0) cered[wid] = ce_acc;
    __syncthreads();
    if (threadIdx.x == 0) {
        float s = 0.0f;
        for (int i = 0; i < wavesPerBlock; ++i) s += cered[i];
        ce_partial[blockIdx.x] = s;
    }
}

// ------- K1b: counting scatter of positive scores into per-class buckets -------
// Per-block LDS histogram -> ONE global atomicAdd per (block,class) -> ordered runs.
__global__ __launch_bounds__(256) void k1b_scatter(
    const int* __restrict__ targets, const float* __restrict__ pos,
    int* __restrict__ cls_cnt, float* __restrict__ bucket, int N)
{
    __shared__ int hist[CC];
    __shared__ int base[CC];
    __shared__ int loc[CC];
    const int tid = threadIdx.x;
    const int rowsPerBlock = N / gridDim.x;
    const int r0 = blockIdx.x * rowsPerBlock;
    const int r1 = r0 + rowsPerBlock;
    for (int c = tid; c < CC; c += blockDim.x) { hist[c] = 0; loc[c] = 0; }
    __syncthreads();
    for (int r = r0 + tid; r < r1; r += blockDim.x)
        atomicAdd(&hist[targets[r]], 1);
    __syncthreads();
    for (int c = tid; c < CC; c += blockDim.x)
        base[c] = (hist[c] > 0) ? atomicAdd(&cls_cnt[c], hist[c]) : 0;
    __syncthreads();
    for (int r = r0 + tid; r < r1; r += blockDim.x) {
        int c = targets[r];
        int idx = base[c] + atomicAdd(&loc[c], 1);
        if (idx < BUCKET) bucket[(size_t)c * BUCKET + idx] = pos[r];
    }
}

// --------- K2: per class, radix-select the m smallest positive scores ---------
__global__ __launch_bounds__(256) void k2_select(
    const float* __restrict__ bucket, const int* __restrict__ cls_cnt,
    float* __restrict__ u, int* __restrict__ m_arr, int* __restrict__ P_arr,
    float* __restrict__ wm_arr)
{
    __shared__ unsigned int keys[BUCKET];     // 16 KB
    __shared__ unsigned int hist[256];
    __shared__ unsigned int sel[256];
    __shared__ unsigned int s_prefix;
    __shared__ int s_rank;
    __shared__ int cnt_lt;
    const int c   = blockIdx.x;
    const int tid = threadIdx.x;
    const int P = min(cls_cnt[c], BUCKET);
    double Kd = 0.95 * (double)P;
    int kf = (int)floor(Kd);
    int m = P - kf;
    if (m > MAXM) m = MAXM;
    if (m < 0) m = 0;
    if (tid == 0) {
        m_arr[c] = m; P_arr[c] = P;
        wm_arr[c] = (float)((double)(kf + 1) - Kd);   // fractional last-step weight
        s_prefix = 0; s_rank = m - 1; cnt_lt = 0;
    }
    // monotone float->uint key: ascending uint order == ascending float order
    for (int i = tid; i < P; i += 256) {
        unsigned int b = __float_as_uint(bucket[(size_t)c * BUCKET + i]);
        keys[i] = (b & 0x80000000u) ? ~b : (b | 0x80000000u);
    }
    __syncthreads();
    if (m == 0) return;                                // uniform exit

    // 4 rounds of 8-bit radix select, MSB first -> exact key of rank m-1
    for (int shift = 24; shift >= 0; shift -= 8) {
        hist[tid] = 0;
        __syncthreads();
        unsigned int pref = s_prefix;
        for (int i = tid; i < P; i += 256) {
            unsigned int k = keys[i];
            bool match = (shift == 24) || ((k >> (shift + 8)) == pref);
            if (match) atomicAdd(&hist[(k >> shift) & 255u], 1u);
        }
        __syncthreads();
        if (tid == 0) {
            int r = s_rank;
            unsigned int cum = 0; int d = 0;
            for (; d < 256; ++d) {
                unsigned int h = hist[d];
                if (cum + h > (unsigned int)r) break;
                cum += h;
            }
            s_rank   = r - (int)cum;
            s_prefix = (pref << 8) | (unsigned int)d;
        }
        __syncthreads();
    }
    const unsigned int kth = s_prefix;

    // collect strictly-less keys (count <= m-1 <= 159), fill ties, pad to 256
    for (int i = tid; i < P; i += 256) {
        unsigned int k = keys[i];
        if (k < kth) {
            int pslot = atomicAdd(&cnt_lt, 1);
            sel[pslot] = k;
        }
    }
    __syncthreads();
    const int nlt = cnt_lt;
    for (int j = nlt + tid; j < 256; j += 256) sel[j] = (j < m) ? kth : 0xFFFFFFFFu;
    __syncthreads();

    // bitonic sort 256 (ascending), 1 element/thread
    for (int kk = 2; kk <= 256; kk <<= 1) {
        for (int j = kk >> 1; j > 0; j >>= 1) {
            int i = tid, ixj = tid ^ j;
            if (ixj > i) {
                unsigned int a = sel[i], b = sel[ixj];
                bool up = ((i & kk) == 0);
                if ((a > b) == up) { sel[i] = b; sel[ixj] = a; }
            }
            __syncthreads();
        }
    }
    if (tid < m) {
        unsigned int k = sel[tid];
        unsigned int b = (k & 0x80000000u) ? (k & 0x7fffffffu) : ~k;
        u[c * MAXM + tid] = __uint_as_float(b);        // m smallest, ascending
    }
}

// --------- K3: stream all scores, count below-threshold contributions ---------
__global__ __launch_bounds__(256) void k3_accum(
    const float4* __restrict__ pred4, const float* __restrict__ L,
    const float* __restrict__ u, const int* __restrict__ m_arr,
    int* __restrict__ g_cnt, int* __restrict__ g_sum, int total4)
{
    __shared__ float umax[CC];
    __shared__ int sm_m[CC];
    __shared__ int ls_cnt[CC], ls_sum[CC];
    for (int c = threadIdx.x; c < CC; c += blockDim.x) {
        int m = m_arr[c];
        sm_m[c] = m;
        umax[c] = (m > 0) ? u[c * MAXM + m - 1] : -INFINITY;
        ls_cnt[c] = 0; ls_sum[c] = 0;
    }
    __syncthreads();
    const int stride = gridDim.x * blockDim.x;
    for (int i = blockIdx.x * blockDim.x + threadIdx.x; i < total4; i += stride) {
        float4 v = pred4[i];
        int n  = i / (CC / 4);                 // 100 % 4 == 0: float4 never crosses a row
        int c0 = (i - n * (CC / 4)) * 4;
        float Ln = L[n];
        float sc[4] = { v.x - Ln, v.y - Ln, v.z - Ln, v.w - Ln };
        #pragma unroll
        for (int q = 0; q < 4; ++q) {
            int c = c0 + q;
            if (sc[q] < umax[c]) {             // ~5% take this path
                int m = sm_m[c];
                const float* uc = u + c * MAXM;
                int l = 0, r = m;              // upper_bound: # thresholds <= sc
                while (l < r) {
                    int mid = (l + r) >> 1;
                    if (uc[mid] <= sc[q]) l = mid + 1; else r = mid;
                }
                atomicAdd(&ls_cnt[c], 1);
                atomicAdd(&ls_sum[c], m - 1 - l);
            }
        }
    }
    __syncthreads();
    for (int c = threadIdx.x; c < CC; c += blockDim.x) {
        if (ls_cnt[c] > 0) {
            atomicAdd(&g_cnt[c], ls_cnt[c]);
            atomicAdd(&g_sum[c], ls_sum[c]);
        }
    }
}

// ---------------- K4: finalize (CE reduce + per-class pAUC + combine) ----------------
__global__ __launch_bounds__(256) void k4_final(
    const float* __restrict__ ce_partial, int nPartial,
    const float* __restrict__ weight, const int* __restrict__ P_arr,
    const int* __restrict__ m_arr, const float* __restrict__ wm_arr,
    const int* __restrict__ g_cnt, const int* __restrict__ g_sum,
    float* __restrict__ out, int N)
{
    __shared__ double r1[256], r2[256], r3[256];
    double ce = 0.0;
    for (int i = threadIdx.x; i < nPartial; i += blockDim.x) ce += (double)ce_partial[i];
    double p = 0.0, wsum = 0.0;
    for (int c = threadIdx.x; c < CC; c += blockDim.x) {
        int P = P_arr[c], m = m_arr[c];
        double wgt = (double)weight[c];
        long long Nn = (long long)N - P;
        if (P > 0 && Nn > 0 && m > 0) {
            double wm = (double)wm_arr[c];
            double S   = (double)g_sum[c] + wm * (double)g_cnt[c];
            double sub = 0.5 * (double)(m - 1) * (double)(m - 2) + wm * (double)(m - 1);
            double pc  = (S - sub) / ((double)Nn * (double)P);
            if (pc < 0.0) pc = 0.0;
            p += pc * wgt;
        }
        wsum += wgt;
    }
    r1[threadIdx.x] = ce; r2[threadIdx.x] = p; r3[threadIdx.x] = wsum;
    __syncthreads();
    for (int off = blockDim.x >> 1; off; off >>= 1) {
        if ((int)threadIdx.x < off) {
            r1[threadIdx.x] += r1[threadIdx.x + off];
            r2[threadIdx.x] += r2[threadIdx.x + off];
            r3[threadIdx.x] += r3[threadIdx.x + off];
        }
        __syncthreads();
    }
    if (threadIdx.x == 0) {
        double ce_loss = r1[0] / (double)N;
        double avg = r2[0] / (r3[0] * 0.05);           // MAX_PAUC = R1-R0 = 0.05
        avg = fmin(fmax(avg, 0.0), 1.0);
        out[0] = (float)(0.5 * ce_loss + 0.5 * (1.0 - avg * avg));
    }
}

extern "C" void kernel_launch(void* const* d_in, const int* in_sizes, int n_in,
                              void* d_out, int out_size, void* d_ws, size_t ws_size,
                              hipStream_t stream) {
    (void)n_in; (void)out_size; (void)ws_size;
    const float* pred    = (const float*)d_in[0];
    const int*   targets = (const int*)d_in[1];
    const float* weight  = (const float*)d_in[2];
    float* out = (float*)d_out;
    const int N = in_sizes[1];

    constexpr int K1_BLOCKS = 4096;
    char* base = (char*)d_ws;
    float* L_ws       = (float*)(base);                               // N floats
    float* pos_ws     = (float*)(base + (size_t)N * 4);               // N floats
    float* ce_partial = (float*)(base + (size_t)N * 8);               // K1_BLOCKS floats
    char* p = base + (size_t)N * 8 + (size_t)K1_BLOCKS * 4;
    float* u      = (float*)p; p += (size_t)CC * MAXM * 4;
    int*   m_arr  = (int*)p;   p += CC * 4;
    int*   P_arr  = (int*)p;   p += CC * 4;
    float* wm_arr = (float*)p; p += CC * 4;
    int*   cls_cnt= (int*)p;   p += CC * 4;   // ---- zeroed region start
    int*   g_cnt  = (int*)p;   p += CC * 4;
    int*   g_sum  = (int*)p;   p += CC * 4;   // ---- zeroed region end
    float* bucket = (float*)p;                // CC*BUCKET floats (1.6 MB)

    hipMemsetAsync(cls_cnt, 0, (size_t)CC * 4 * 3, stream);           // cls_cnt+g_cnt+g_sum

    k1_rowstats<<<K1_BLOCKS, 256, 0, stream>>>(pred, targets, weight, L_ws, pos_ws,
                                               ce_partial, N);
    k1b_scatter<<<256, 256, 0, stream>>>(targets, pos_ws, cls_cnt, bucket, N);
    k2_select<<<CC, 256, 0, stream>>>(bucket, cls_cnt, u, m_arr, P_arr, wm_arr);
    const int total4 = (int)((size_t)N * CC / 4);
    k3_accum<<<2048, 256, 0, stream>>>((const float4*)pred, L_ws, u, m_arr,
                                       g_cnt, g_sum, total4);
    k4_final<<<1, 256, 0, stream>>>(ce_partial, K1_BLOCKS, weight, P_arr, m_arr, wm_arr,
                                    g_cnt, g_sum, out, N);
}

// Round 4
// 261.889 us; speedup vs baseline: 4.1439x; 1.3219x over previous
//
#include <hip/hip_runtime.h>
#include <math.h>

#define WAVE 64
constexpr int   CC      = 100;    // classes (fixed by problem)
constexpr int   MAXM    = 160;    // max thresholds per class (~0.05*P+1 ~= 132)
constexpr int   BUCKET  = 4096;   // per-class positive-score bucket capacity (P ~ 2621 +- 51)
constexpr int   USTRIDE = 161;    // LDS stride for u table (161 mod 32 != 0 -> spread banks)
constexpr int   LCAP    = 4096;   // per-block LDS compaction buffer (expected ~1300)
constexpr float LSMOOTH = 0.1f;
constexpr int   TILE    = 64;     // k1 rows per block

// ---------------- K1: LDS-tiled softmax stats ----------------
// Stage 64 rows via coalesced float4 (HBM-bound), then 16-lane groups reduce
// from LDS. Row stride 100 floats: groups g'=0..3 land on 2 bank cosets -> free.
__global__ __launch_bounds__(256) void k1_tile(
    const float* __restrict__ pred, const int* __restrict__ targets,
    const float* __restrict__ weight, float* __restrict__ L_out,
    float* __restrict__ pos_out, float* __restrict__ ce_partial, int N)
{
    __shared__ float tile[TILE * CC];      // 25.6 KB
    __shared__ int   ttgt[TILE];
    __shared__ float tL[TILE], tpos[TILE];
    __shared__ float cered[4];
    const int tid = threadIdx.x;
    const int r0  = blockIdx.x * TILE;

    // stage: 64 rows x 25 float4, fully coalesced
    const float4* src = (const float4*)(pred + (size_t)r0 * CC);
    #pragma unroll
    for (int t = tid; t < TILE * (CC / 4); t += 256)
        *((float4*)&tile[t * 4]) = src[t];
    if (tid < TILE) ttgt[tid] = targets[r0 + tid];
    __syncthreads();

    const int x = tid & 15;                // lane within 16-wide row group
    const int G = tid >> 4;                // group 0..15
    float w[7];
    #pragma unroll
    for (int j = 0; j < 7; ++j) {
        int c = x + 16 * j;
        w[j] = (c < CC) ? weight[c] : 0.0f;
    }
    float Wl = 0.0f;
    #pragma unroll
    for (int j = 0; j < 7; ++j) Wl += w[j];
    #pragma unroll
    for (int off = 1; off < 16; off <<= 1) Wl += __shfl_xor(Wl, off, 16);

    float ce_acc = 0.0f;
    #pragma unroll
    for (int rr = 0; rr < 4; ++rr) {
        const int r = G * 4 + rr;
        const float* rp = tile + r * CC;
        float v[7];
        #pragma unroll
        for (int j = 0; j < 7; ++j) {
            int c = x + 16 * j;
            v[j] = (c < CC) ? rp[c] : -INFINITY;
        }
        float vmax = v[0];
        #pragma unroll
        for (int j = 1; j < 7; ++j) vmax = fmaxf(vmax, v[j]);
        #pragma unroll
        for (int off = 1; off < 16; off <<= 1) vmax = fmaxf(vmax, __shfl_xor(vmax, off, 16));
        float z = 0.0f, ws = 0.0f;
        #pragma unroll
        for (int j = 0; j < 7; ++j) {
            int c = x + 16 * j;
            if (c < CC) { z += __expf(v[j] - vmax); ws += w[j] * v[j]; }
        }
        #pragma unroll
        for (int off = 1; off < 16; off <<= 1) {
            z  += __shfl_xor(z,  off, 16);
            ws += __shfl_xor(ws, off, 16);
        }
        float L = vmax + __logf(z);
        if (x == 0) {
            int t = ttgt[r];
            float pt = rp[t];
            tL[r] = L; tpos[r] = pt - L;
            ce_acc += -((1.0f - LSMOOTH) * weight[t] * (pt - L)
                        + (LSMOOTH / CC) * (ws - Wl * L));
        }
    }
    // reduce ce_acc (nonzero on x==0 lanes only) across wave, then block
    #pragma unroll
    for (int off = 32; off; off >>= 1) ce_acc += __shfl_xor(ce_acc, off, WAVE);
    if ((tid & 63) == 0) cered[tid >> 6] = ce_acc;
    __syncthreads();
    if (tid < TILE) {                          // coalesced output
        L_out[r0 + tid]   = tL[tid];
        pos_out[r0 + tid] = tpos[tid];
    }
    if (tid == 0)
        ce_partial[blockIdx.x] = cered[0] + cered[1] + cered[2] + cered[3];
}

// ------- K1b: counting scatter of positive scores into per-class buckets -------
__global__ __launch_bounds__(256) void k1b_scatter(
    const int* __restrict__ targets, const float* __restrict__ pos,
    int* __restrict__ cls_cnt, float* __restrict__ bucket, int N)
{
    __shared__ int hist[CC];
    __shared__ int base[CC];
    __shared__ int loc[CC];
    const int tid = threadIdx.x;
    const int rowsPerBlock = N / gridDim.x;
    const int r0 = blockIdx.x * rowsPerBlock;
    const int r1 = r0 + rowsPerBlock;
    for (int c = tid; c < CC; c += blockDim.x) { hist[c] = 0; loc[c] = 0; }
    __syncthreads();
    for (int r = r0 + tid; r < r1; r += blockDim.x)
        atomicAdd(&hist[targets[r]], 1);
    __syncthreads();
    for (int c = tid; c < CC; c += blockDim.x)
        base[c] = (hist[c] > 0) ? atomicAdd(&cls_cnt[c], hist[c]) : 0;
    __syncthreads();
    for (int r = r0 + tid; r < r1; r += blockDim.x) {
        int c = targets[r];
        int idx = base[c] + atomicAdd(&loc[c], 1);
        if (idx < BUCKET) bucket[(size_t)c * BUCKET + idx] = pos[r];
    }
}

// --------- K2: per class, radix-select the m smallest positive scores ---------
__global__ __launch_bounds__(256) void k2_select(
    const float* __restrict__ bucket, const int* __restrict__ cls_cnt,
    float* __restrict__ u, int* __restrict__ m_arr, int* __restrict__ P_arr,
    float* __restrict__ wm_arr)
{
    __shared__ unsigned int keys[BUCKET];     // 16 KB
    __shared__ unsigned int hist[256];
    __shared__ unsigned int scan[256];
    __shared__ unsigned int sel[256];
    __shared__ unsigned int s_prefix;
    __shared__ int s_rank;
    __shared__ int cnt_lt;
    const int c   = blockIdx.x;
    const int tid = threadIdx.x;
    const int P = min(cls_cnt[c], BUCKET);
    double Kd = 0.95 * (double)P;
    int kf = (int)floor(Kd);
    int m = P - kf;
    if (m > MAXM) m = MAXM;
    if (m < 0) m = 0;
    if (tid == 0) {
        m_arr[c] = m; P_arr[c] = P;
        wm_arr[c] = (float)((double)(kf + 1) - Kd);   // fractional last-step weight
        s_prefix = 0; s_rank = m - 1; cnt_lt = 0;
    }
    // monotone float->uint key
    for (int i = tid; i < P; i += 256) {
        unsigned int b = __float_as_uint(bucket[(size_t)c * BUCKET + i]);
        keys[i] = (b & 0x80000000u) ? ~b : (b | 0x80000000u);
    }
    __syncthreads();
    if (m == 0) return;                                // uniform exit

    // 4 rounds of 8-bit MSB radix select; digit pick via parallel scan
    for (int shift = 24; shift >= 0; shift -= 8) {
        hist[tid] = 0;
        __syncthreads();
        unsigned int pref = s_prefix;
        for (int i = tid; i < P; i += 256) {
            unsigned int k = keys[i];
            bool match = (shift == 24) || ((k >> (shift + 8)) == pref);
            if (match) atomicAdd(&hist[(k >> shift) & 255u], 1u);
        }
        __syncthreads();
        scan[tid] = hist[tid];
        __syncthreads();
        for (int off = 1; off < 256; off <<= 1) {      // Hillis-Steele inclusive scan
            unsigned int add = (tid >= off) ? scan[tid - off] : 0u;
            __syncthreads();
            scan[tid] += add;
            __syncthreads();
        }
        int r = s_rank;
        unsigned int inc = scan[tid];
        unsigned int exc = inc - hist[tid];
        __syncthreads();
        if ((unsigned int)r >= exc && (unsigned int)r < inc) {   // unique thread
            s_rank   = r - (int)exc;
            s_prefix = (pref << 8) | (unsigned int)tid;
        }
        __syncthreads();
    }
    const unsigned int kth = s_prefix;

    // collect strictly-less keys, fill ties, pad to 256
    for (int i = tid; i < P; i += 256) {
        unsigned int k = keys[i];
        if (k < kth) {
            int pslot = atomicAdd(&cnt_lt, 1);
            sel[pslot] = k;
        }
    }
    __syncthreads();
    const int nlt = cnt_lt;
    for (int j = nlt + tid; j < 256; j += 256) sel[j] = (j < m) ? kth : 0xFFFFFFFFu;
    __syncthreads();
    // bitonic sort 256 ascending
    for (int kk = 2; kk <= 256; kk <<= 1) {
        for (int j = kk >> 1; j > 0; j >>= 1) {
            int i = tid, ixj = tid ^ j;
            if (ixj > i) {
                unsigned int a = sel[i], b = sel[ixj];
                bool up = ((i & kk) == 0);
                if ((a > b) == up) { sel[i] = b; sel[ixj] = a; }
            }
            __syncthreads();
        }
    }
    if (tid < m) {
        unsigned int k = sel[tid];
        unsigned int b = (k & 0x80000000u) ? (k & 0x7fffffffu) : ~k;
        u[c * MAXM + tid] = __uint_as_float(b);        // m smallest, ascending
    }
}

// branchless uniform upper_bound: returns #{i < m : uc[i*stride... wait flat} <= key
__device__ __forceinline__ int ubound(const float* uc, int m, float key, int maxidx) {
    int l = 0;
    #pragma unroll
    for (int s = 128; s; s >>= 1) {
        int p = l + s - 1;
        float val = uc[p < maxidx ? p : maxidx];
        l += ((p < m) && (val <= key)) ? s : 0;
    }
    return l;
}

// --------- K3a: stream scores, compact qualifiers (c, sc) into global list ---------
__global__ __launch_bounds__(256) void k3a_stream(
    const float4* __restrict__ pred4, const float* __restrict__ L,
    const float* __restrict__ u, const int* __restrict__ m_arr,
    uint2* __restrict__ list, int* __restrict__ list_cnt, int list_cap,
    int* __restrict__ g_cnt, int* __restrict__ g_sum, int total4)
{
    __shared__ float umax_s[CC];
    __shared__ uint2 buf[LCAP];               // 32 KB
    __shared__ int lcnt;
    __shared__ int gbase;
    const int tid = threadIdx.x;
    if (tid < CC) {
        int m = m_arr[tid];
        umax_s[tid] = (m > 0) ? u[tid * MAXM + m - 1] : -INFINITY;
    }
    if (tid == 0) lcnt = 0;
    __syncthreads();

    const int stride = gridDim.x * blockDim.x;
    int i = blockIdx.x * blockDim.x + tid;
    int j = i % 25;                            // float4 col within row
    int n = i / 25;                            // row
    const int dj = stride % 25, dn = stride / 25;
    while (i < total4) {
        float4 v = pred4[i];
        float Ln = L[n];
        float4 um = *((const float4*)&umax_s[j * 4]);
        float s0 = v.x - Ln, s1 = v.y - Ln, s2 = v.z - Ln, s3 = v.w - Ln;
        #pragma unroll
        for (int q = 0; q < 4; ++q) {
            float sc = (q == 0) ? s0 : (q == 1) ? s1 : (q == 2) ? s2 : s3;
            float mx = (q == 0) ? um.x : (q == 1) ? um.y : (q == 2) ? um.z : um.w;
            if (sc < mx) {
                int c = j * 4 + q;
                int idx = atomicAdd(&lcnt, 1);
                if (idx < LCAP) {
                    buf[idx] = make_uint2((unsigned int)c, __float_as_uint(sc));
                } else {                       // LDS overflow (shouldn't happen): inline exact
                    int m = m_arr[c];
                    int l = ubound(u + c * MAXM, m, sc, MAXM - 1);
                    atomicAdd(&g_cnt[c], 1);
                    atomicAdd(&g_sum[c], m - 1 - l);
                }
            }
        }
        i += stride; j += dj; n += dn;
        if (j >= 25) { j -= 25; n += 1; }
    }
    __syncthreads();
    int cnt = min(lcnt, LCAP);
    if (tid == 0) gbase = atomicAdd(list_cnt, cnt);
    __syncthreads();
    const int base0 = gbase;
    for (int k = tid; k < cnt; k += 256) {
        int gi = base0 + k;
        if (gi < list_cap) {
            list[gi] = buf[k];
        } else {                               // global overflow: inline exact
            uint2 e = buf[k];
            int c = (int)e.x; float sc = __uint_as_float(e.y);
            int m = m_arr[c];
            int l = ubound(u + c * MAXM, m, sc, MAXM - 1);
            atomicAdd(&g_cnt[c], 1);
            atomicAdd(&g_sum[c], m - 1 - l);
        }
    }
}

// --------- K3b: rank compacted entries against LDS-staged u table ---------
__global__ __launch_bounds__(256) void k3b_rank(
    const uint2* __restrict__ list, const int* __restrict__ list_cnt, int list_cap,
    const float* __restrict__ u, const int* __restrict__ m_arr,
    int* __restrict__ g_cnt, int* __restrict__ g_sum)
{
    __shared__ float us[CC * USTRIDE];         // 64.4 KB, stride 161 spreads banks
    __shared__ int sm[CC];
    __shared__ int lcnt[CC], lsum[CC];
    const int tid = threadIdx.x;
    for (int c = tid; c < CC; c += 256) { sm[c] = m_arr[c]; lcnt[c] = 0; lsum[c] = 0; }
    for (int t = tid; t < CC * MAXM; t += 256) {
        int c = t / MAXM, k = t - c * MAXM;
        us[c * USTRIDE + k] = u[t];
    }
    __syncthreads();
    const int n = min(*list_cnt, list_cap);
    const int stride = gridDim.x * blockDim.x;
    for (int idx = blockIdx.x * blockDim.x + tid; idx < n; idx += stride) {
        uint2 e = list[idx];
        int c = (int)e.x;
        float key = __uint_as_float(e.y);
        int m = sm[c];
        int l = ubound(us + c * USTRIDE, m, key, USTRIDE - 1);
        atomicAdd(&lcnt[c], 1);
        atomicAdd(&lsum[c], m - 1 - l);
    }
    __syncthreads();
    for (int c = tid; c < CC; c += 256) {
        if (lcnt[c]) { atomicAdd(&g_cnt[c], lcnt[c]); atomicAdd(&g_sum[c], lsum[c]); }
    }
}

// ---------------- K4: finalize ----------------
__global__ __launch_bounds__(256) void k4_final(
    const float* __restrict__ ce_partial, int nPartial,
    const float* __restrict__ weight, const int* __restrict__ P_arr,
    const int* __restrict__ m_arr, const float* __restrict__ wm_arr,
    const int* __restrict__ g_cnt, const int* __restrict__ g_sum,
    float* __restrict__ out, int N)
{
    __shared__ double r1[256], r2[256], r3[256];
    double ce = 0.0;
    for (int i = threadIdx.x; i < nPartial; i += blockDim.x) ce += (double)ce_partial[i];
    double p = 0.0, wsum = 0.0;
    for (int c = threadIdx.x; c < CC; c += blockDim.x) {
        int P = P_arr[c], m = m_arr[c];
        double wgt = (double)weight[c];
        long long Nn = (long long)N - P;
        if (P > 0 && Nn > 0 && m > 0) {
            double wm = (double)wm_arr[c];
            double S   = (double)g_sum[c] + wm * (double)g_cnt[c];
            double sub = 0.5 * (double)(m - 1) * (double)(m - 2) + wm * (double)(m - 1);
            double pc  = (S - sub) / ((double)Nn * (double)P);
            if (pc < 0.0) pc = 0.0;
            p += pc * wgt;
        }
        wsum += wgt;
    }
    r1[threadIdx.x] = ce; r2[threadIdx.x] = p; r3[threadIdx.x] = wsum;
    __syncthreads();
    for (int off = blockDim.x >> 1; off; off >>= 1) {
        if ((int)threadIdx.x < off) {
            r1[threadIdx.x] += r1[threadIdx.x + off];
            r2[threadIdx.x] += r2[threadIdx.x + off];
            r3[threadIdx.x] += r3[threadIdx.x + off];
        }
        __syncthreads();
    }
    if (threadIdx.x == 0) {
        double ce_loss = r1[0] / (double)N;
        double avg = r2[0] / (r3[0] * 0.05);           // MAX_PAUC = R1-R0 = 0.05
        avg = fmin(fmax(avg, 0.0), 1.0);
        out[0] = (float)(0.5 * ce_loss + 0.5 * (1.0 - avg * avg));
    }
}

extern "C" void kernel_launch(void* const* d_in, const int* in_sizes, int n_in,
                              void* d_out, int out_size, void* d_ws, size_t ws_size,
                              hipStream_t stream) {
    (void)n_in; (void)out_size;
    const float* pred    = (const float*)d_in[0];
    const int*   targets = (const int*)d_in[1];
    const float* weight  = (const float*)d_in[2];
    float* out = (float*)d_out;
    const int N = in_sizes[1];

    const int K1_BLOCKS = N / TILE;                    // 4096
    char* base = (char*)d_ws;
    size_t off = 0;
    auto take = [&](size_t bytes) { char* q = base + off; off += (bytes + 15) & ~(size_t)15; return q; };
    float* L_ws       = (float*)take((size_t)N * 4);
    float* pos_ws     = (float*)take((size_t)N * 4);
    float* ce_partial = (float*)take((size_t)K1_BLOCKS * 4);
    float* u          = (float*)take((size_t)CC * MAXM * 4);
    int*   m_arr      = (int*)take(CC * 4);
    int*   P_arr      = (int*)take(CC * 4);
    float* wm_arr     = (float*)take(CC * 4);
    int*   zero_blk   = (int*)take(304 * 4);           // cls_cnt|g_cnt|g_sum|list_cnt
    int*   cls_cnt  = zero_blk;
    int*   g_cnt    = zero_blk + CC;
    int*   g_sum    = zero_blk + 2 * CC;
    int*   list_cnt = zero_blk + 3 * CC;
    float* bucket     = (float*)take((size_t)CC * BUCKET * 4);   // 1.6 MB
    uint2* list       = (uint2*)(base + off);
    long long rem     = (long long)ws_size - (long long)off;
    int list_cap      = (rem > 0) ? (int)(rem / 8) : 0;          // expected need ~1.3M entries

    hipMemsetAsync(zero_blk, 0, 304 * 4, stream);

    k1_tile<<<K1_BLOCKS, 256, 0, stream>>>(pred, targets, weight, L_ws, pos_ws,
                                           ce_partial, N);
    k1b_scatter<<<256, 256, 0, stream>>>(targets, pos_ws, cls_cnt, bucket, N);
    k2_select<<<CC, 256, 0, stream>>>(bucket, cls_cnt, u, m_arr, P_arr, wm_arr);
    const int total4 = (int)((size_t)N * CC / 4);
    k3a_stream<<<1024, 256, 0, stream>>>((const float4*)pred, L_ws, u, m_arr,
                                         list, list_cnt, list_cap, g_cnt, g_sum, total4);
    k3b_rank<<<512, 256, 0, stream>>>(list, list_cnt, list_cap, u, m_arr, g_cnt, g_sum);
    k4_final<<<1, 256, 0, stream>>>(ce_partial, K1_BLOCKS, weight, P_arr, m_arr, wm_arr,
                                    g_cnt, g_sum, out, N);
}